// Round 1
// baseline (3577.932 us; speedup 1.0000x reference)
//
#include <hip/hip_runtime.h>
#include <cstddef>
#include <cstdint>

// ---------------------------------------------------------------------------
// BatchGRU: bidirectional GRU over ragged segments (B=2048 segs, H=300, L=128,
// N=131072 total rows). Persistent-segment design: one block = 16 segments x
// one direction; recurrence runs entirely inside the block (no grid sync).
// GEMMs in bf16 MFMA 16x16x32, fp32 accum, fp32 h master state in LDS.
// ---------------------------------------------------------------------------

typedef short s8v __attribute__((ext_vector_type(8)));   // 8 x bf16 (bits)
typedef float f4v __attribute__((ext_vector_type(4)));   // MFMA accum

#define NSEG   2048
#define HID    300
#define HPAD   320
#define MAXLEN 128

__device__ __forceinline__ short f2bf(float f){
  unsigned u = __float_as_uint(f);
  u = (u + 0x7FFFu + ((u >> 16) & 1u)) >> 16;   // RNE
  return (short)u;
}
__device__ __forceinline__ float sigm(float x){ return 1.f / (1.f + __expf(-x)); }
__device__ __forceinline__ float tanha(float x){ return 1.f - 2.f / (__expf(2.f * x) + 1.f); }

// ---------------------------------------------------------------------------
// starts[b] = exclusive prefix sum of a_scope
// ---------------------------------------------------------------------------
__global__ __launch_bounds__(1024)
void scan_starts_k(const int* __restrict__ a_scope, int* __restrict__ starts){
  __shared__ int buf[2][NSEG];
  const int tid = threadIdx.x;
  for (int i = tid; i < NSEG; i += 1024) buf[0][i] = a_scope[i];
  __syncthreads();
  int src = 0;
  for (int off = 1; off < NSEG; off <<= 1){
    for (int i = tid; i < NSEG; i += 1024){
      int v = buf[src][i];
      if (i >= off) v += buf[src][i - off];
      buf[1 - src][i] = v;
    }
    __syncthreads();
    src ^= 1;
  }
  for (int i = tid; i < NSEG; i += 1024) starts[i] = buf[src][i] - a_scope[i];
}

// ---------------------------------------------------------------------------
// h0[b][k] = max over t<len of raw node[starts[b]+t][k]  (k>=HID -> 0 pad)
// ---------------------------------------------------------------------------
__global__ void h0_max_k(const float* __restrict__ node, const int* __restrict__ a_scope,
                         const int* __restrict__ starts, float* __restrict__ h0){
  const int b = blockIdx.x;
  const int k = threadIdx.x;              // 320 threads
  const int s = starts[b], len = a_scope[b];
  float m = 0.f;
  if (k < HID){
    m = -3.402823466e38f;
    const float* p = node + (size_t)s * HID + k;
    for (int t = 0; t < len; ++t) m = fmaxf(m, p[(size_t)t * HID]);
  }
  h0[(size_t)b * HPAD + k] = m;
}

// ---------------------------------------------------------------------------
// Pack weights into MFMA B-fragment order, bf16.
// PkA: [dir][sec(r=0,z=1)][jt 0..19][kt 0..19][lane 0..63][e 0..7]
//      k<320 -> w_ih rows (sec*300+j), k in [320,640) -> w_hh rows; zero pad.
// PkB: [dir][sec(xn=0,hn=1)][jt 0..19][kt 0..9][lane][e]
//      xn: w_ih rows 600+j ; hn: w_hh rows 600+j ; K=320.
// gbias: [dir][4][320]  (r: b_ih+b_hh, z: b_ih+b_hh, xn: b_ih, hn: b_hh)
// B-fragment lane map: row g = jt*16 + (lane&15); k = kt*32 + (lane>>4)*8 + e.
// ---------------------------------------------------------------------------
__global__ void prep_k(const float* __restrict__ wih_f, const float* __restrict__ whh_f,
                       const float* __restrict__ bih_f, const float* __restrict__ bhh_f,
                       const float* __restrict__ wih_b, const float* __restrict__ whh_b,
                       const float* __restrict__ bih_b, const float* __restrict__ bhh_b,
                       short* __restrict__ PkA, short* __restrict__ PkB,
                       float* __restrict__ gbias){
  const int idx = blockIdx.x * 256 + threadIdx.x;
  if (idx < 819200){                                     // PkA
    int e = idx & 7, lane = (idx >> 3) & 63;
    int r = idx >> 9;
    int kt = r % 20; r /= 20;
    int jt = r % 20; r /= 20;
    int sec = r & 1, d = r >> 1;
    const float* wih = d ? wih_b : wih_f;
    const float* whh = d ? whh_b : whh_f;
    int j = jt * 16 + (lane & 15);
    int k = kt * 32 + (lane >> 4) * 8 + e;
    float v = 0.f;
    if (j < HID){
      int row = sec * HID + j;
      if (k < HID)                    v = wih[row * HID + k];
      else if (k >= 320 && k < 620)   v = whh[row * HID + (k - 320)];
    }
    PkA[idx] = f2bf(v);
  } else if (idx < 819200 + 409600){                     // PkB
    int t = idx - 819200;
    int e = t & 7, lane = (t >> 3) & 63;
    int r = t >> 9;
    int kt = r % 10; r /= 10;
    int jt = r % 20; r /= 20;
    int sec = r & 1, d = r >> 1;
    const float* w = sec ? (d ? whh_b : whh_f) : (d ? wih_b : wih_f);
    int j = jt * 16 + (lane & 15);
    int k = kt * 32 + (lane >> 4) * 8 + e;
    float v = 0.f;
    if (j < HID && k < HID) v = w[(600 + j) * HID + k];
    PkB[t] = f2bf(v);
  } else if (idx < 819200 + 409600 + 2560){              // biases
    int r3 = idx - 819200 - 409600;
    int d = r3 / 1280;
    int rem = r3 - d * 1280;
    int sec = rem / HPAD;
    int j = rem - sec * HPAD;
    const float* bih = d ? bih_b : bih_f;
    const float* bhh = d ? bhh_b : bhh_f;
    float v = 0.f;
    if (j < HID){
      if (sec == 0)      v = bih[j] + bhh[j];
      else if (sec == 1) v = bih[HID + j] + bhh[HID + j];
      else if (sec == 2) v = bih[2 * HID + j];
      else               v = bhh[2 * HID + j];
    }
    gbias[r3] = v;
  }
}

// ---------------------------------------------------------------------------
// Persistent GRU kernel. blockIdx: bit0 = dir, rest = segment group of 16.
// 256 threads = 4 waves; wave w owns gate-column slice j in [w*80, w*80+80)
// for all 4 sections (r,z,xn,hn) -> elementwise update needs no cross-wave
// exchange (r/z/xn/hn for a given (m,j) land in the same lane+reg).
// MFMA maps (verified): A[m=lane&15][k=quad*8+j], B[n=lane&15][k=quad*8+j],
// D col=lane&15, row=quad*4+reg.
// ---------------------------------------------------------------------------
__global__ __launch_bounds__(256)
void gru_k(const float* __restrict__ node, const float* __restrict__ bias,
           const int* __restrict__ a_scope, const int* __restrict__ starts,
           const float* __restrict__ h0, const short* __restrict__ PkA,
           const short* __restrict__ PkB, const float* __restrict__ gbias,
           float* __restrict__ out){
  __shared__ __align__(16) short xbuf[16][328];   // bf16 x_t   (stride-staggered banks)
  __shared__ __align__(16) short hbuf[16][328];   // bf16 h     (MFMA A operand)
  __shared__ float hfp[16][324];                  // fp32 h master
  __shared__ float lbias[4][HPAD];
  __shared__ int ls[16], ll[16];

  const int dir  = blockIdx.x & 1;
  const int seg0 = (blockIdx.x >> 1) * 16;
  const int tid  = threadIdx.x;
  const int wave = tid >> 6;
  const int lane = tid & 63;
  const int quad = lane >> 4;
  const int lc   = lane & 15;
  const int l8   = lane << 3;

  if (tid < 16){ ls[tid] = starts[seg0 + tid]; ll[tid] = a_scope[seg0 + tid]; }
  for (int i = tid; i < 4 * HPAD; i += 256) ((float*)lbias)[i] = gbias[dir * (4 * HPAD) + i];
  for (int i = tid; i < 16 * HPAD; i += 256){
    int m = i / HPAD, k = i - m * HPAD;
    float v = h0[(size_t)(seg0 + m) * HPAD + k];
    hfp[m][k] = v;
    hbuf[m][k] = f2bf(v);
  }
  __syncthreads();

  const short* PA = PkA + (size_t)dir * 409600;   // [2][20][20][512]
  const short* PB = PkB + (size_t)dir * 204800;   // [2][20][10][512]

  const int xm = tid >> 4, xu = tid & 15;

  for (int step = 0; step < MAXLEN; ++step){
    const int t = dir ? (MAXLEN - 1 - step) : step;

    // ---- stage x_t = relu(node+bias) (zeros for padding rows) into LDS ----
    {
      const bool valid = t < ll[xm];
      const float* src = node + (size_t)(ls[xm] + t) * HID;
      for (int k = xu; k < HPAD; k += 16){
        float v = 0.f;
        if (valid && k < HID){
          v = src[k] + bias[k];
          v = v > 0.f ? v : 0.f;
        }
        xbuf[xm][k] = f2bf(v);
      }
    }
    __syncthreads();   // xbuf ready; prev-step hbuf writes visible

    // ---- MFMA: 4 gate sections, K split into x-half and h-half ----
    f4v aR[5], aZ[5], aX[5], aH[5];
    #pragma unroll
    for (int i = 0; i < 5; ++i){
      aR[i] = f4v{0.f,0.f,0.f,0.f}; aZ[i] = f4v{0.f,0.f,0.f,0.f};
      aX[i] = f4v{0.f,0.f,0.f,0.f}; aH[i] = f4v{0.f,0.f,0.f,0.f};
    }

    #pragma unroll 2
    for (int kt = 0; kt < 10; ++kt){          // x contribution (k 0..319)
      const int k0 = kt * 32 + quad * 8;
      const s8v a = *(const s8v*)&xbuf[lc][k0];
      #pragma unroll
      for (int i = 0; i < 5; ++i){
        const int jt = wave * 5 + i;
        const s8v bR = *(const s8v*)(PA + (size_t)((jt)      * 20 + kt) * 512 + l8);
        aR[i] = __builtin_amdgcn_mfma_f32_16x16x32_bf16(a, bR, aR[i], 0, 0, 0);
        const s8v bZ = *(const s8v*)(PA + (size_t)((20 + jt) * 20 + kt) * 512 + l8);
        aZ[i] = __builtin_amdgcn_mfma_f32_16x16x32_bf16(a, bZ, aZ[i], 0, 0, 0);
        const s8v bX = *(const s8v*)(PB + (size_t)((jt)      * 10 + kt) * 512 + l8);
        aX[i] = __builtin_amdgcn_mfma_f32_16x16x32_bf16(a, bX, aX[i], 0, 0, 0);
      }
    }
    #pragma unroll 2
    for (int kt = 0; kt < 10; ++kt){          // h contribution (k 320..639)
      const int k0 = kt * 32 + quad * 8;
      const s8v a = *(const s8v*)&hbuf[lc][k0];
      #pragma unroll
      for (int i = 0; i < 5; ++i){
        const int jt = wave * 5 + i;
        const s8v bR = *(const s8v*)(PA + (size_t)((jt)      * 20 + 10 + kt) * 512 + l8);
        aR[i] = __builtin_amdgcn_mfma_f32_16x16x32_bf16(a, bR, aR[i], 0, 0, 0);
        const s8v bZ = *(const s8v*)(PA + (size_t)((20 + jt) * 20 + 10 + kt) * 512 + l8);
        aZ[i] = __builtin_amdgcn_mfma_f32_16x16x32_bf16(a, bZ, aZ[i], 0, 0, 0);
        const s8v bH = *(const s8v*)(PB + (size_t)((20 + jt) * 10 + kt) * 512 + l8);
        aH[i] = __builtin_amdgcn_mfma_f32_16x16x32_bf16(a, bH, aH[i], 0, 0, 0);
      }
    }
    __syncthreads();   // all waves done reading hbuf before it is rewritten

    // ---- gates + h update + output write ----
    #pragma unroll
    for (int i = 0; i < 5; ++i){
      const int j = wave * 80 + i * 16 + lc;
      if (j < HID){
        const float bR = lbias[0][j], bZ = lbias[1][j];
        const float bX = lbias[2][j], bH = lbias[3][j];
        #pragma unroll
        for (int r = 0; r < 4; ++r){
          const int m = quad * 4 + r;
          const float rg = sigm(aR[i][r] + bR);
          const float zg = sigm(aZ[i][r] + bZ);
          const float ng = tanha(aX[i][r] + bX + rg * (aH[i][r] + bH));
          const float hold = hfp[m][j];
          const float hnew = (1.f - zg) * ng + zg * hold;
          hfp[m][j] = hnew;
          hbuf[m][j] = f2bf(hnew);
          if (t < ll[m])
            out[(size_t)(ls[m] + t) * 600 + dir * 300 + j] = hnew;
        }
      }
    }
    // next iteration's post-stage-x __syncthreads orders hbuf writes vs GEMM
  }
}

// ---------------------------------------------------------------------------
extern "C" void kernel_launch(void* const* d_in, const int* in_sizes, int n_in,
                              void* d_out, int out_size, void* d_ws, size_t ws_size,
                              hipStream_t stream){
  const float* node    = (const float*)d_in[0];
  const int*   a_scope = (const int*)  d_in[1];
  // d_in[2] = max_len (always 128, hardcoded)
  const float* bias    = (const float*)d_in[3];
  const float* wih_f   = (const float*)d_in[4];
  const float* whh_f   = (const float*)d_in[5];
  const float* bih_f   = (const float*)d_in[6];
  const float* bhh_f   = (const float*)d_in[7];
  const float* wih_b   = (const float*)d_in[8];
  const float* whh_b   = (const float*)d_in[9];
  const float* bih_b   = (const float*)d_in[10];
  const float* bhh_b   = (const float*)d_in[11];
  float* out = (float*)d_out;

  char* ws = (char*)d_ws;
  int*   starts = (int*)  (ws + 0);          //   8,192 B
  float* h0     = (float*)(ws + 8192);       // 2,621,440 B
  short* PkA    = (short*)(ws + 2629632);    // 1,638,400 B
  short* PkB    = (short*)(ws + 4268032);    //   819,200 B
  float* gbias  = (float*)(ws + 5087232);    //    10,240 B  (total ~4.9 MB)

  scan_starts_k<<<1, 1024, 0, stream>>>(a_scope, starts);
  prep_k<<<(819200 + 409600 + 2560 + 255) / 256, 256, 0, stream>>>(
      wih_f, whh_f, bih_f, bhh_f, wih_b, whh_b, bih_b, bhh_b, PkA, PkB, gbias);
  h0_max_k<<<NSEG, HPAD, 0, stream>>>(node, a_scope, starts, h0);
  gru_k<<<256, 256, 0, stream>>>(node, bias, a_scope, starts, h0, PkA, PkB, gbias, out);
}

// Round 3
// 2737.740 us; speedup vs baseline: 1.3069x; 1.3069x over previous
//
#include <hip/hip_runtime.h>
#include <cstddef>
#include <cstdint>

// ---------------------------------------------------------------------------
// BatchGRU round 3: round-2 design with the per-dir pack-stride bug fixed.
// prep2_k packs PkH/PkI as [dir][sec][jt][kt][lane][e] -> per-dir stride is
// 3*20*10*512 = 307200 shorts. Round 2 used 614400 (total size) in the
// consumers, so dir=1 read the gbias/xp poison region as weights -> NaN.
// ---------------------------------------------------------------------------

typedef short s8v __attribute__((ext_vector_type(8)));   // 8 x bf16 (bits)
typedef float f4v __attribute__((ext_vector_type(4)));   // MFMA accum

#define NSEG   2048
#define HID    300
#define HPAD   320
#define MAXLEN 128
#define NTOT   131072
#define PKSTRIDE 307200   // shorts per dir in PkH / PkI

__device__ __forceinline__ short f2bf(float f){
  unsigned u = __float_as_uint(f);
  u = (u + 0x7FFFu + ((u >> 16) & 1u)) >> 16;   // RNE
  return (short)u;
}
__device__ __forceinline__ float bf2f(unsigned short u){
  return __uint_as_float((unsigned)u << 16);
}
__device__ __forceinline__ float sigm(float x){ return 1.f / (1.f + __expf(-x)); }
__device__ __forceinline__ float tanha(float x){ return 1.f - 2.f / (__expf(2.f * x) + 1.f); }

// ---------------------------------------------------------------------------
// starts[b] = exclusive prefix sum of a_scope
// ---------------------------------------------------------------------------
__global__ __launch_bounds__(1024)
void scan_starts_k(const int* __restrict__ a_scope, int* __restrict__ starts){
  __shared__ int buf[2][NSEG];
  const int tid = threadIdx.x;
  for (int i = tid; i < NSEG; i += 1024) buf[0][i] = a_scope[i];
  __syncthreads();
  int src = 0;
  for (int off = 1; off < NSEG; off <<= 1){
    for (int i = tid; i < NSEG; i += 1024){
      int v = buf[src][i];
      if (i >= off) v += buf[src][i - off];
      buf[1 - src][i] = v;
    }
    __syncthreads();
    src ^= 1;
  }
  for (int i = tid; i < NSEG; i += 1024) starts[i] = buf[src][i] - a_scope[i];
}

// ---------------------------------------------------------------------------
// h0[b][k] = max over t<len of raw node[starts[b]+t][k]  (k>=HID -> 0 pad)
// ---------------------------------------------------------------------------
__global__ void h0_max_k(const float* __restrict__ node, const int* __restrict__ a_scope,
                         const int* __restrict__ starts, float* __restrict__ h0){
  const int b = blockIdx.x;
  const int k = threadIdx.x;              // 320 threads
  const int s = starts[b], len = a_scope[b];
  float m = 0.f;
  if (k < HID){
    m = -3.402823466e38f;
    const float* p = node + (size_t)s * HID + k;
    for (int t = 0; t < len; ++t) m = fmaxf(m, p[(size_t)t * HID]);
  }
  h0[(size_t)b * HPAD + k] = m;
}

// ===========================================================================
// FAST PATH
// ===========================================================================
// prep2: pack W_hh (PkH) and W_ih (PkI) into MFMA B-fragment order, bf16.
// Layout: [dir][sec 0..2 (r,z,n)][jt 0..19][kt 0..9][lane 0..63][e 0..7]
// B lane map: j = jt*16 + (lane&15); k = kt*32 + (lane>>4)*8 + e; K padded 320.
// gbias: [dir][4][320]  (r: bih+bhh, z: bih+bhh, xn: bih, hn: bhh)
// ---------------------------------------------------------------------------
__global__ void prep2_k(const float* __restrict__ wih_f, const float* __restrict__ whh_f,
                        const float* __restrict__ bih_f, const float* __restrict__ bhh_f,
                        const float* __restrict__ wih_b, const float* __restrict__ whh_b,
                        const float* __restrict__ bih_b, const float* __restrict__ bhh_b,
                        short* __restrict__ PkH, short* __restrict__ PkI,
                        float* __restrict__ gbias){
  const int idx = blockIdx.x * 256 + threadIdx.x;
  if (idx < 1228800){
    const bool isH = idx < 614400;
    int t = isH ? idx : idx - 614400;
    int e = t & 7, lane = (t >> 3) & 63;
    int r = t >> 9;
    int kt = r % 10; r /= 10;
    int jt = r % 20; r /= 20;
    int sec = r % 3, d = r / 3;          // per-dir stride = PKSTRIDE shorts
    const float* w = isH ? (d ? whh_b : whh_f) : (d ? wih_b : wih_f);
    int j = jt * 16 + (lane & 15);
    int k = kt * 32 + (lane >> 4) * 8 + e;
    float v = 0.f;
    if (j < HID && k < HID) v = w[(sec * HID + j) * HID + k];
    (isH ? PkH : PkI)[t] = f2bf(v);
  } else if (idx < 1228800 + 2560){
    int r3 = idx - 1228800;
    int d = r3 / 1280;
    int rem = r3 - d * 1280;
    int sec = rem / HPAD;
    int j = rem - sec * HPAD;
    const float* bih = d ? bih_b : bih_f;
    const float* bhh = d ? bhh_b : bhh_f;
    float v = 0.f;
    if (j < HID){
      if (sec == 0)      v = bih[j] + bhh[j];
      else if (sec == 1) v = bih[HID + j] + bhh[HID + j];
      else if (sec == 2) v = bih[2 * HID + j];
      else               v = bhh[2 * HID + j];
    }
    gbias[r3] = v;
  }
}

// ---------------------------------------------------------------------------
// xp GEMM: xp[dir][row][g] = (relu(node[row]+bias) @ W_ih_dir^T)[g], bf16.
// Block = 256 thr / 4 waves; each wave owns 2 M-tiles (32 rows); block = 128
// rows. B fragments staged 4 output-tiles at a time through LDS so each B
// byte is fetched once per block (not once per wave).
// ---------------------------------------------------------------------------
__global__ __launch_bounds__(256)
void xp_gemm_k(const float* __restrict__ node, const float* __restrict__ bias,
               const short* __restrict__ PkI, short* __restrict__ xp){
  __shared__ __align__(16) short Bt[4 * 5120];   // 40 KB: 4 tiles x [10 kt][512]
  const int dir = blockIdx.x & 1;
  const int blk = blockIdx.x >> 1;               // 0..1023
  const int tid = threadIdx.x;
  const int wave = tid >> 6, lane = tid & 63;
  const int quad = lane >> 4, lc = lane & 15, l8 = lane << 3;
  const int rowbase = blk * 128 + wave * 32;
  const short* PI = PkI + (size_t)dir * PKSTRIDE;
  short* xpd = xp + (size_t)dir * ((size_t)NTOT * 900);

  // A fragments in registers: 2 tiles x 10 kt (rows read once, fp32->relu->bf16)
  s8v A[2][10];
  #pragma unroll
  for (int tm = 0; tm < 2; ++tm){
    const float* src = node + (size_t)(rowbase + tm * 16 + lc) * HID;
    #pragma unroll
    for (int kt = 0; kt < 10; ++kt){
      const int k0 = kt * 32 + quad * 8;
      s8v a;
      #pragma unroll
      for (int e = 0; e < 8; ++e){
        const int k = k0 + e;
        float v = 0.f;
        if (k < HID){ v = src[k] + bias[k]; v = v > 0.f ? v : 0.f; }
        a[e] = f2bf(v);
      }
      A[tm][kt] = a;
    }
  }

  for (int st0 = 0; st0 < 60; st0 += 4){
    __syncthreads();
    for (int i = tid; i < 2560; i += 256)
      ((s8v*)Bt)[i] = ((const s8v*)(PI + (size_t)st0 * 5120))[i];
    __syncthreads();
    #pragma unroll
    for (int u = 0; u < 4; ++u){
      const int st = st0 + u;                 // st = sec*20 + jt
      const int sec = st / 20, jt = st % 20;
      f4v a0 = {0.f,0.f,0.f,0.f}, a1 = {0.f,0.f,0.f,0.f};
      #pragma unroll
      for (int kt = 0; kt < 10; ++kt){
        const s8v b = *(const s8v*)&Bt[u * 5120 + kt * 512 + l8];
        a0 = __builtin_amdgcn_mfma_f32_16x16x32_bf16(A[0][kt], b, a0, 0, 0, 0);
        a1 = __builtin_amdgcn_mfma_f32_16x16x32_bf16(A[1][kt], b, a1, 0, 0, 0);
      }
      const int j = jt * 16 + lc;
      if (j < HID){
        const int g = sec * HID + j;
        #pragma unroll
        for (int r = 0; r < 4; ++r){
          const int rr = rowbase + quad * 4 + r;
          xpd[(size_t)rr * 900 + g]        = f2bf(a0[r]);
          xpd[(size_t)(rr + 16) * 900 + g] = f2bf(a1[r]);
        }
      }
    }
  }
}

// ---------------------------------------------------------------------------
// Recurrent kernel (fast path): h-GEMM only. 256 blocks (128 seg-groups x 2
// dirs), 16 segs/block, 4 waves; wave w owns gate columns [w*80, w*80+80).
// Per step/wave: 150 MFMA (3 sec x 5 jt x 10 kt), B = 600 KB/step/block.
// xp preactivations loaded per-thread at step start (h-independent prefetch).
// ---------------------------------------------------------------------------
__global__ __launch_bounds__(256)
void gru2_k(const int* __restrict__ a_scope, const int* __restrict__ starts,
            const float* __restrict__ h0, const short* __restrict__ PkH,
            const float* __restrict__ gbias, const short* __restrict__ xp,
            float* __restrict__ out){
  __shared__ __align__(16) short hbuf[16][328];   // bf16 h (A operand)
  __shared__ float hfp[16][324];                  // fp32 h master
  __shared__ float lbias[4][HPAD];
  __shared__ int ls[16], ll[16];

  const int dir  = blockIdx.x & 1;
  const int seg0 = (blockIdx.x >> 1) * 16;
  const int tid  = threadIdx.x;
  const int wave = tid >> 6;
  const int lane = tid & 63;
  const int quad = lane >> 4;
  const int lc   = lane & 15;
  const int l8   = lane << 3;

  if (tid < 16){ ls[tid] = starts[seg0 + tid]; ll[tid] = a_scope[seg0 + tid]; }
  for (int i = tid; i < 4 * HPAD; i += 256) ((float*)lbias)[i] = gbias[dir * 4 * HPAD + i];
  for (int i = tid; i < 16 * HPAD; i += 256){
    int m = i / HPAD, k = i - m * HPAD;
    float v = h0[(size_t)(seg0 + m) * HPAD + k];
    hfp[m][k] = v;
    hbuf[m][k] = f2bf(v);
  }
  __syncthreads();

  const short* PH = PkH + (size_t)dir * PKSTRIDE;
  const unsigned short* xpd = (const unsigned short*)xp + (size_t)dir * ((size_t)NTOT * 900);

  for (int step = 0; step < MAXLEN; ++step){
    const int t = dir ? (MAXLEN - 1 - step) : step;

    // ---- xp gate preactivations (independent of h) ----
    float xr[5][4], xz[5][4], xn[5][4];
    #pragma unroll
    for (int i = 0; i < 5; ++i){
      const int j = wave * 80 + i * 16 + lc;
      const bool jv = j < HID;
      #pragma unroll
      for (int r = 0; r < 4; ++r){
        const int m = quad * 4 + r;
        float vr = 0.f, vz = 0.f, vn = 0.f;
        if (jv && t < ll[m]){
          const unsigned short* p = xpd + (size_t)(ls[m] + t) * 900 + j;
          vr = bf2f(p[0]); vz = bf2f(p[300]); vn = bf2f(p[600]);
        }
        xr[i][r] = vr; xz[i][r] = vz; xn[i][r] = vn;
      }
    }

    __syncthreads();   // prev-step hbuf writes visible

    // ---- h-GEMM: 3 gate sections, K=320 ----
    f4v aR[5], aZ[5], aN[5];
    #pragma unroll
    for (int i = 0; i < 5; ++i){
      aR[i] = f4v{0.f,0.f,0.f,0.f};
      aZ[i] = f4v{0.f,0.f,0.f,0.f};
      aN[i] = f4v{0.f,0.f,0.f,0.f};
    }
    #pragma unroll 2
    for (int kt = 0; kt < 10; ++kt){
      const int k0 = kt * 32 + quad * 8;
      const s8v a = *(const s8v*)&hbuf[lc][k0];
      #pragma unroll
      for (int i = 0; i < 5; ++i){
        const int jt = wave * 5 + i;
        const s8v bR = *(const s8v*)(PH + (size_t)(( 0 + jt) * 10 + kt) * 512 + l8);
        aR[i] = __builtin_amdgcn_mfma_f32_16x16x32_bf16(a, bR, aR[i], 0, 0, 0);
        const s8v bZ = *(const s8v*)(PH + (size_t)((20 + jt) * 10 + kt) * 512 + l8);
        aZ[i] = __builtin_amdgcn_mfma_f32_16x16x32_bf16(a, bZ, aZ[i], 0, 0, 0);
        const s8v bN = *(const s8v*)(PH + (size_t)((40 + jt) * 10 + kt) * 512 + l8);
        aN[i] = __builtin_amdgcn_mfma_f32_16x16x32_bf16(a, bN, aN[i], 0, 0, 0);
      }
    }
    __syncthreads();   // all reads of hbuf done before rewrite

    // ---- gates + h update + output ----
    #pragma unroll
    for (int i = 0; i < 5; ++i){
      const int j = wave * 80 + i * 16 + lc;
      if (j < HID){
        const float bR = lbias[0][j], bZ = lbias[1][j];
        const float bX = lbias[2][j], bH = lbias[3][j];
        #pragma unroll
        for (int r = 0; r < 4; ++r){
          const int m = quad * 4 + r;
          const float rg = sigm(aR[i][r] + bR + xr[i][r]);
          const float zg = sigm(aZ[i][r] + bZ + xz[i][r]);
          const float ng = tanha(xn[i][r] + bX + rg * (aN[i][r] + bH));
          const float hold = hfp[m][j];
          const float hnew = (1.f - zg) * ng + zg * hold;
          hfp[m][j] = hnew;
          hbuf[m][j] = f2bf(hnew);
          if (t < ll[m])
            out[(size_t)(ls[m] + t) * 600 + dir * HID + j] = hnew;
        }
      }
    }
  }
}

// ===========================================================================
// FALLBACK PATH (round-1, known-passing) — used when ws_size is too small.
// ===========================================================================
__global__ void prep_k(const float* __restrict__ wih_f, const float* __restrict__ whh_f,
                       const float* __restrict__ bih_f, const float* __restrict__ bhh_f,
                       const float* __restrict__ wih_b, const float* __restrict__ whh_b,
                       const float* __restrict__ bih_b, const float* __restrict__ bhh_b,
                       short* __restrict__ PkA, short* __restrict__ PkB,
                       float* __restrict__ gbias){
  const int idx = blockIdx.x * 256 + threadIdx.x;
  if (idx < 819200){
    int e = idx & 7, lane = (idx >> 3) & 63;
    int r = idx >> 9;
    int kt = r % 20; r /= 20;
    int jt = r % 20; r /= 20;
    int sec = r & 1, d = r >> 1;
    const float* wih = d ? wih_b : wih_f;
    const float* whh = d ? whh_b : whh_f;
    int j = jt * 16 + (lane & 15);
    int k = kt * 32 + (lane >> 4) * 8 + e;
    float v = 0.f;
    if (j < HID){
      int row = sec * HID + j;
      if (k < HID)                    v = wih[row * HID + k];
      else if (k >= 320 && k < 620)   v = whh[row * HID + (k - 320)];
    }
    PkA[idx] = f2bf(v);
  } else if (idx < 819200 + 409600){
    int t = idx - 819200;
    int e = t & 7, lane = (t >> 3) & 63;
    int r = t >> 9;
    int kt = r % 10; r /= 10;
    int jt = r % 20; r /= 20;
    int sec = r & 1, d = r >> 1;
    const float* w = sec ? (d ? whh_b : whh_f) : (d ? wih_b : wih_f);
    int j = jt * 16 + (lane & 15);
    int k = kt * 32 + (lane >> 4) * 8 + e;
    float v = 0.f;
    if (j < HID && k < HID) v = w[(600 + j) * HID + k];
    PkB[t] = f2bf(v);
  } else if (idx < 819200 + 409600 + 2560){
    int r3 = idx - 819200 - 409600;
    int d = r3 / 1280;
    int rem = r3 - d * 1280;
    int sec = rem / HPAD;
    int j = rem - sec * HPAD;
    const float* bih = d ? bih_b : bih_f;
    const float* bhh = d ? bhh_b : bhh_f;
    float v = 0.f;
    if (j < HID){
      if (sec == 0)      v = bih[j] + bhh[j];
      else if (sec == 1) v = bih[HID + j] + bhh[HID + j];
      else if (sec == 2) v = bih[2 * HID + j];
      else               v = bhh[2 * HID + j];
    }
    gbias[r3] = v;
  }
}

__global__ __launch_bounds__(256)
void gru_k(const float* __restrict__ node, const float* __restrict__ bias,
           const int* __restrict__ a_scope, const int* __restrict__ starts,
           const float* __restrict__ h0, const short* __restrict__ PkA,
           const short* __restrict__ PkB, const float* __restrict__ gbias,
           float* __restrict__ out){
  __shared__ __align__(16) short xbuf[16][328];
  __shared__ __align__(16) short hbuf[16][328];
  __shared__ float hfp[16][324];
  __shared__ float lbias[4][HPAD];
  __shared__ int ls[16], ll[16];

  const int dir  = blockIdx.x & 1;
  const int seg0 = (blockIdx.x >> 1) * 16;
  const int tid  = threadIdx.x;
  const int wave = tid >> 6;
  const int lane = tid & 63;
  const int quad = lane >> 4;
  const int lc   = lane & 15;
  const int l8   = lane << 3;

  if (tid < 16){ ls[tid] = starts[seg0 + tid]; ll[tid] = a_scope[seg0 + tid]; }
  for (int i = tid; i < 4 * HPAD; i += 256) ((float*)lbias)[i] = gbias[dir * (4 * HPAD) + i];
  for (int i = tid; i < 16 * HPAD; i += 256){
    int m = i / HPAD, k = i - m * HPAD;
    float v = h0[(size_t)(seg0 + m) * HPAD + k];
    hfp[m][k] = v;
    hbuf[m][k] = f2bf(v);
  }
  __syncthreads();

  const short* PA = PkA + (size_t)dir * 409600;
  const short* PB = PkB + (size_t)dir * 204800;
  const int xm = tid >> 4, xu = tid & 15;

  for (int step = 0; step < MAXLEN; ++step){
    const int t = dir ? (MAXLEN - 1 - step) : step;
    {
      const bool valid = t < ll[xm];
      const float* src = node + (size_t)(ls[xm] + t) * HID;
      for (int k = xu; k < HPAD; k += 16){
        float v = 0.f;
        if (valid && k < HID){
          v = src[k] + bias[k];
          v = v > 0.f ? v : 0.f;
        }
        xbuf[xm][k] = f2bf(v);
      }
    }
    __syncthreads();

    f4v aR[5], aZ[5], aX[5], aH[5];
    #pragma unroll
    for (int i = 0; i < 5; ++i){
      aR[i] = f4v{0.f,0.f,0.f,0.f}; aZ[i] = f4v{0.f,0.f,0.f,0.f};
      aX[i] = f4v{0.f,0.f,0.f,0.f}; aH[i] = f4v{0.f,0.f,0.f,0.f};
    }
    #pragma unroll 2
    for (int kt = 0; kt < 10; ++kt){
      const int k0 = kt * 32 + quad * 8;
      const s8v a = *(const s8v*)&xbuf[lc][k0];
      #pragma unroll
      for (int i = 0; i < 5; ++i){
        const int jt = wave * 5 + i;
        const s8v bR = *(const s8v*)(PA + (size_t)((jt)      * 20 + kt) * 512 + l8);
        aR[i] = __builtin_amdgcn_mfma_f32_16x16x32_bf16(a, bR, aR[i], 0, 0, 0);
        const s8v bZ = *(const s8v*)(PA + (size_t)((20 + jt) * 20 + kt) * 512 + l8);
        aZ[i] = __builtin_amdgcn_mfma_f32_16x16x32_bf16(a, bZ, aZ[i], 0, 0, 0);
        const s8v bX = *(const s8v*)(PB + (size_t)((jt)      * 10 + kt) * 512 + l8);
        aX[i] = __builtin_amdgcn_mfma_f32_16x16x32_bf16(a, bX, aX[i], 0, 0, 0);
      }
    }
    #pragma unroll 2
    for (int kt = 0; kt < 10; ++kt){
      const int k0 = kt * 32 + quad * 8;
      const s8v a = *(const s8v*)&hbuf[lc][k0];
      #pragma unroll
      for (int i = 0; i < 5; ++i){
        const int jt = wave * 5 + i;
        const s8v bR = *(const s8v*)(PA + (size_t)((jt)      * 20 + 10 + kt) * 512 + l8);
        aR[i] = __builtin_amdgcn_mfma_f32_16x16x32_bf16(a, bR, aR[i], 0, 0, 0);
        const s8v bZ = *(const s8v*)(PA + (size_t)((20 + jt) * 20 + 10 + kt) * 512 + l8);
        aZ[i] = __builtin_amdgcn_mfma_f32_16x16x32_bf16(a, bZ, aZ[i], 0, 0, 0);
        const s8v bH = *(const s8v*)(PB + (size_t)((20 + jt) * 10 + kt) * 512 + l8);
        aH[i] = __builtin_amdgcn_mfma_f32_16x16x32_bf16(a, bH, aH[i], 0, 0, 0);
      }
    }
    __syncthreads();

    #pragma unroll
    for (int i = 0; i < 5; ++i){
      const int j = wave * 80 + i * 16 + lc;
      if (j < HID){
        const float bR = lbias[0][j], bZ = lbias[1][j];
        const float bX = lbias[2][j], bH = lbias[3][j];
        #pragma unroll
        for (int r = 0; r < 4; ++r){
          const int m = quad * 4 + r;
          const float rg = sigm(aR[i][r] + bR);
          const float zg = sigm(aZ[i][r] + bZ);
          const float ng = tanha(aX[i][r] + bX + rg * (aH[i][r] + bH));
          const float hold = hfp[m][j];
          const float hnew = (1.f - zg) * ng + zg * hold;
          hfp[m][j] = hnew;
          hbuf[m][j] = f2bf(hnew);
          if (t < ll[m])
            out[(size_t)(ls[m] + t) * 600 + dir * HID + j] = hnew;
        }
      }
    }
  }
}

// ---------------------------------------------------------------------------
extern "C" void kernel_launch(void* const* d_in, const int* in_sizes, int n_in,
                              void* d_out, int out_size, void* d_ws, size_t ws_size,
                              hipStream_t stream){
  const float* node    = (const float*)d_in[0];
  const int*   a_scope = (const int*)  d_in[1];
  // d_in[2] = max_len (always 128, hardcoded)
  const float* bias    = (const float*)d_in[3];
  const float* wih_f   = (const float*)d_in[4];
  const float* whh_f   = (const float*)d_in[5];
  const float* bih_f   = (const float*)d_in[6];
  const float* bhh_f   = (const float*)d_in[7];
  const float* wih_b   = (const float*)d_in[8];
  const float* whh_b   = (const float*)d_in[9];
  const float* bih_b   = (const float*)d_in[10];
  const float* bhh_b   = (const float*)d_in[11];
  float* out = (float*)d_out;

  char* ws = (char*)d_ws;
  int*   starts = (int*)  (ws + 0);          //     8,192 B
  float* h0     = (float*)(ws + 8192);       // 2,621,440 B -> 2,629,632

  scan_starts_k<<<1, 1024, 0, stream>>>(a_scope, starts);
  h0_max_k<<<NSEG, HPAD, 0, stream>>>(node, a_scope, starts, h0);

  const size_t FAST_NEED = 476956672ull;     // ~477 MB (xp bf16 both dirs)
  if (ws_size >= FAST_NEED){
    short* PkH = (short*)(ws + 2629632);     // 1,228,800 B
    short* PkI = (short*)(ws + 3858432);     // 1,228,800 B
    float* gb  = (float*)(ws + 5087232);     //    10,240 B
    short* xpb = (short*)(ws + 5097472);     // 471,859,200 B
    prep2_k<<<4810, 256, 0, stream>>>(wih_f, whh_f, bih_f, bhh_f,
                                      wih_b, whh_b, bih_b, bhh_b, PkH, PkI, gb);
    xp_gemm_k<<<2048, 256, 0, stream>>>(node, bias, PkI, xpb);
    gru2_k<<<256, 256, 0, stream>>>(a_scope, starts, h0, PkH, gb, xpb, out);
  } else {
    short* PkA   = (short*)(ws + 2629632);   // 1,638,400 B
    short* PkB   = (short*)(ws + 4268032);   //   819,200 B
    float* gbias = (float*)(ws + 5087232);   //    10,240 B
    prep_k<<<4810, 256, 0, stream>>>(wih_f, whh_f, bih_f, bhh_f,
                                     wih_b, whh_b, bih_b, bhh_b, PkA, PkB, gbias);
    gru_k<<<256, 256, 0, stream>>>(node, bias, a_scope, starts, h0, PkA, PkB, gbias, out);
  }
}

// Round 4
// 2160.491 us; speedup vs baseline: 1.6561x; 1.2672x over previous
//
#include <hip/hip_runtime.h>
#include <cstddef>
#include <cstdint>

// ---------------------------------------------------------------------------
// BatchGRU round 4: fix the recurrent kernel's L2-concurrency limit.
// Round-3 gru2_k had 4 waves/CU each streaming 150 B-fragments/step ->
// ~22 B/cyc/CU effective (latency-bound). gru3_k: 640 threads / 10 waves,
// N-split 2 jt-tiles per wave (wave 9: 1; jt 19 = all-padding, skipped).
// Each wave owns its gate columns end-to-end: no reduction, h/biases in regs,
// LDS = hbuf only. 2.5x outstanding loads at identical weight traffic.
// ---------------------------------------------------------------------------

typedef short s8v __attribute__((ext_vector_type(8)));   // 8 x bf16 (bits)
typedef float f4v __attribute__((ext_vector_type(4)));   // MFMA accum

#define NSEG   2048
#define HID    300
#define HPAD   320
#define MAXLEN 128
#define NTOT   131072
#define PKSTRIDE 307200   // shorts per dir in PkH / PkI

__device__ __forceinline__ short f2bf(float f){
  unsigned u = __float_as_uint(f);
  u = (u + 0x7FFFu + ((u >> 16) & 1u)) >> 16;   // RNE
  return (short)u;
}
__device__ __forceinline__ float bf2f(unsigned short u){
  return __uint_as_float((unsigned)u << 16);
}
__device__ __forceinline__ float sigm(float x){ return 1.f / (1.f + __expf(-x)); }
__device__ __forceinline__ float tanha(float x){ return 1.f - 2.f / (__expf(2.f * x) + 1.f); }

// ---------------------------------------------------------------------------
// starts[b] = exclusive prefix sum of a_scope
// ---------------------------------------------------------------------------
__global__ __launch_bounds__(1024)
void scan_starts_k(const int* __restrict__ a_scope, int* __restrict__ starts){
  __shared__ int buf[2][NSEG];
  const int tid = threadIdx.x;
  for (int i = tid; i < NSEG; i += 1024) buf[0][i] = a_scope[i];
  __syncthreads();
  int src = 0;
  for (int off = 1; off < NSEG; off <<= 1){
    for (int i = tid; i < NSEG; i += 1024){
      int v = buf[src][i];
      if (i >= off) v += buf[src][i - off];
      buf[1 - src][i] = v;
    }
    __syncthreads();
    src ^= 1;
  }
  for (int i = tid; i < NSEG; i += 1024) starts[i] = buf[src][i] - a_scope[i];
}

// ---------------------------------------------------------------------------
// h0[b][k] = max over t<len of raw node[starts[b]+t][k]  (k>=HID -> 0 pad)
// ---------------------------------------------------------------------------
__global__ void h0_max_k(const float* __restrict__ node, const int* __restrict__ a_scope,
                         const int* __restrict__ starts, float* __restrict__ h0){
  const int b = blockIdx.x;
  const int k = threadIdx.x;              // 320 threads
  const int s = starts[b], len = a_scope[b];
  float m = 0.f;
  if (k < HID){
    m = -3.402823466e38f;
    const float* p = node + (size_t)s * HID + k;
    for (int t = 0; t < len; ++t) m = fmaxf(m, p[(size_t)t * HID]);
  }
  h0[(size_t)b * HPAD + k] = m;
}

// ===========================================================================
// FAST PATH
// ===========================================================================
// prep2: pack W_hh (PkH) and W_ih (PkI) into MFMA B-fragment order, bf16.
// Layout: [dir][sec 0..2 (r,z,n)][jt 0..19][kt 0..9][lane 0..63][e 0..7]
// B lane map: j = jt*16 + (lane&15); k = kt*32 + (lane>>4)*8 + e; K padded 320.
// gbias: [dir][4][320]  (r: bih+bhh, z: bih+bhh, xn: bih, hn: bhh)
// ---------------------------------------------------------------------------
__global__ void prep2_k(const float* __restrict__ wih_f, const float* __restrict__ whh_f,
                        const float* __restrict__ bih_f, const float* __restrict__ bhh_f,
                        const float* __restrict__ wih_b, const float* __restrict__ whh_b,
                        const float* __restrict__ bih_b, const float* __restrict__ bhh_b,
                        short* __restrict__ PkH, short* __restrict__ PkI,
                        float* __restrict__ gbias){
  const int idx = blockIdx.x * 256 + threadIdx.x;
  if (idx < 1228800){
    const bool isH = idx < 614400;
    int t = isH ? idx : idx - 614400;
    int e = t & 7, lane = (t >> 3) & 63;
    int r = t >> 9;
    int kt = r % 10; r /= 10;
    int jt = r % 20; r /= 20;
    int sec = r % 3, d = r / 3;          // per-dir stride = PKSTRIDE shorts
    const float* w = isH ? (d ? whh_b : whh_f) : (d ? wih_b : wih_f);
    int j = jt * 16 + (lane & 15);
    int k = kt * 32 + (lane >> 4) * 8 + e;
    float v = 0.f;
    if (j < HID && k < HID) v = w[(sec * HID + j) * HID + k];
    (isH ? PkH : PkI)[t] = f2bf(v);
  } else if (idx < 1228800 + 2560){
    int r3 = idx - 1228800;
    int d = r3 / 1280;
    int rem = r3 - d * 1280;
    int sec = rem / HPAD;
    int j = rem - sec * HPAD;
    const float* bih = d ? bih_b : bih_f;
    const float* bhh = d ? bhh_b : bhh_f;
    float v = 0.f;
    if (j < HID){
      if (sec == 0)      v = bih[j] + bhh[j];
      else if (sec == 1) v = bih[HID + j] + bhh[HID + j];
      else if (sec == 2) v = bih[2 * HID + j];
      else               v = bhh[2 * HID + j];
    }
    gbias[r3] = v;
  }
}

// ---------------------------------------------------------------------------
// xp GEMM: xp[dir][row][g] = (relu(node[row]+bias) @ W_ih_dir^T)[g], bf16.
// Block = 256 thr / 4 waves; each wave owns 2 M-tiles (32 rows); block = 128
// rows. B fragments staged 4 output-tiles at a time through LDS so each B
// byte is fetched once per block (not once per wave).
// ---------------------------------------------------------------------------
__global__ __launch_bounds__(256)
void xp_gemm_k(const float* __restrict__ node, const float* __restrict__ bias,
               const short* __restrict__ PkI, short* __restrict__ xp){
  __shared__ __align__(16) short Bt[4 * 5120];   // 40 KB: 4 tiles x [10 kt][512]
  const int dir = blockIdx.x & 1;
  const int blk = blockIdx.x >> 1;               // 0..1023
  const int tid = threadIdx.x;
  const int wave = tid >> 6, lane = tid & 63;
  const int quad = lane >> 4, lc = lane & 15, l8 = lane << 3;
  const int rowbase = blk * 128 + wave * 32;
  const short* PI = PkI + (size_t)dir * PKSTRIDE;
  short* xpd = xp + (size_t)dir * ((size_t)NTOT * 900);

  // A fragments in registers: 2 tiles x 10 kt (rows read once, fp32->relu->bf16)
  s8v A[2][10];
  #pragma unroll
  for (int tm = 0; tm < 2; ++tm){
    const float* src = node + (size_t)(rowbase + tm * 16 + lc) * HID;
    #pragma unroll
    for (int kt = 0; kt < 10; ++kt){
      const int k0 = kt * 32 + quad * 8;
      s8v a;
      #pragma unroll
      for (int e = 0; e < 8; ++e){
        const int k = k0 + e;
        float v = 0.f;
        if (k < HID){ v = src[k] + bias[k]; v = v > 0.f ? v : 0.f; }
        a[e] = f2bf(v);
      }
      A[tm][kt] = a;
    }
  }

  for (int st0 = 0; st0 < 60; st0 += 4){
    __syncthreads();
    for (int i = tid; i < 2560; i += 256)
      ((s8v*)Bt)[i] = ((const s8v*)(PI + (size_t)st0 * 5120))[i];
    __syncthreads();
    #pragma unroll
    for (int u = 0; u < 4; ++u){
      const int st = st0 + u;                 // st = sec*20 + jt
      const int sec = st / 20, jt = st % 20;
      f4v a0 = {0.f,0.f,0.f,0.f}, a1 = {0.f,0.f,0.f,0.f};
      #pragma unroll
      for (int kt = 0; kt < 10; ++kt){
        const s8v b = *(const s8v*)&Bt[u * 5120 + kt * 512 + l8];
        a0 = __builtin_amdgcn_mfma_f32_16x16x32_bf16(A[0][kt], b, a0, 0, 0, 0);
        a1 = __builtin_amdgcn_mfma_f32_16x16x32_bf16(A[1][kt], b, a1, 0, 0, 0);
      }
      const int j = jt * 16 + lc;
      if (j < HID){
        const int g = sec * HID + j;
        #pragma unroll
        for (int r = 0; r < 4; ++r){
          const int rr = rowbase + quad * 4 + r;
          xpd[(size_t)rr * 900 + g]        = f2bf(a0[r]);
          xpd[(size_t)(rr + 16) * 900 + g] = f2bf(a1[r]);
        }
      }
    }
  }
}

// ---------------------------------------------------------------------------
// Recurrent kernel round 4: 256 blocks (128 seg-groups x 2 dirs), 16 segs
// per block, 640 threads / 10 waves. Wave w owns jt tiles {2w, 2w+1}
// (wave 9: jt 18 only; jt 19 is all j>=300 padding, skipped entirely).
// Per wave/step: <=60 B-frag loads (was 150) at unchanged block-level weight
// traffic -> 2.5x memory concurrency. No cross-wave reduction: gate math,
// fp32 h master, and biases live in the owning thread's registers.
// LDS = bf16 hbuf only (A operand, shared by all waves).
// ---------------------------------------------------------------------------
__global__ __launch_bounds__(640)
void gru3_k(const int* __restrict__ a_scope, const int* __restrict__ starts,
            const float* __restrict__ h0, const short* __restrict__ PkH,
            const float* __restrict__ gbias, const short* __restrict__ xp,
            float* __restrict__ out){
  __shared__ __align__(16) short hbuf[16][328];   // bf16 h (A operand)

  const int dir  = blockIdx.x & 1;
  const int seg0 = (blockIdx.x >> 1) * 16;
  const int tid  = threadIdx.x;
  const int wave = tid >> 6;
  const int lane = tid & 63;
  const int quad = lane >> 4;
  const int lc   = lane & 15;
  const int l8   = lane << 3;
  const int jt0  = 2 * wave;

  // per-thread segment rows (m = quad*4 + r)
  int ls_r[4], ll_r[4];
  #pragma unroll
  for (int r = 0; r < 4; ++r){
    const int m = quad * 4 + r;
    ls_r[r] = starts[seg0 + m];
    ll_r[r] = a_scope[seg0 + m];
  }

  // init hbuf cooperatively (16 x 320 entries over 640 threads)
  for (int i = tid; i < 16 * HPAD; i += 640){
    const int m = i / HPAD, k = i - m * HPAD;
    hbuf[m][k] = f2bf(h0[(size_t)(seg0 + m) * HPAD + k]);
  }

  // per-thread h master + biases in registers (columns j = (jt0+i)*16 + lc)
  float hprev[2][4];
  float bR[2], bZ[2], bX[2], bH[2];
  bool  jv[2];
  #pragma unroll
  for (int i = 0; i < 2; ++i){
    const int jt = jt0 + i;
    const int j  = jt * 16 + lc;
    jv[i] = (jt < 19) && (j < HID);
    bR[i] = bZ[i] = bX[i] = bH[i] = 0.f;
    hprev[i][0] = hprev[i][1] = hprev[i][2] = hprev[i][3] = 0.f;
    if (jv[i]){
      bR[i] = gbias[dir * 1280 + 0 * HPAD + j];
      bZ[i] = gbias[dir * 1280 + 1 * HPAD + j];
      bX[i] = gbias[dir * 1280 + 2 * HPAD + j];
      bH[i] = gbias[dir * 1280 + 3 * HPAD + j];
      #pragma unroll
      for (int r = 0; r < 4; ++r)
        hprev[i][r] = h0[(size_t)(seg0 + quad * 4 + r) * HPAD + j];
    }
  }
  __syncthreads();

  const short* PH = PkH + (size_t)dir * PKSTRIDE;
  const unsigned short* xpd = (const unsigned short*)xp + (size_t)dir * ((size_t)NTOT * 900);
  const int njt = (jt0 < 18) ? 2 : 1;   // wave 9 handles jt 18 only

  for (int step = 0; step < MAXLEN; ++step){
    const int t = dir ? (MAXLEN - 1 - step) : step;

    // ---- xp gate preactivations (h-independent; overlap with MFMA stream) --
    float xg[2][4][3];
    #pragma unroll
    for (int i = 0; i < 2; ++i){
      const int j = (jt0 + i) * 16 + lc;
      #pragma unroll
      for (int r = 0; r < 4; ++r){
        float vr = 0.f, vz = 0.f, vn = 0.f;
        if (jv[i] && t < ll_r[r]){
          const unsigned short* p = xpd + (size_t)(ls_r[r] + t) * 900 + j;
          vr = bf2f(p[0]); vz = bf2f(p[300]); vn = bf2f(p[600]);
        }
        xg[i][r][0] = vr; xg[i][r][1] = vz; xg[i][r][2] = vn;
      }
    }

    __syncthreads();   // hbuf(t) complete (written end of previous step)

    // ---- h-GEMM: acc[i][sec], K=320 over 10 kt ----
    f4v acc[2][3];
    #pragma unroll
    for (int i = 0; i < 2; ++i)
      #pragma unroll
      for (int s = 0; s < 3; ++s)
        acc[i][s] = f4v{0.f, 0.f, 0.f, 0.f};

    #pragma unroll 2
    for (int kt = 0; kt < 10; ++kt){
      const s8v a = *(const s8v*)&hbuf[lc][kt * 32 + quad * 8];
      #pragma unroll
      for (int i = 0; i < 2; ++i){
        if (i < njt){
          const int jt = jt0 + i;
          #pragma unroll
          for (int s = 0; s < 3; ++s){
            const s8v b = *(const s8v*)(PH + (size_t)((s * 20 + jt) * 10 + kt) * 512 + l8);
            acc[i][s] = __builtin_amdgcn_mfma_f32_16x16x32_bf16(a, b, acc[i][s], 0, 0, 0);
          }
        }
      }
    }
    __syncthreads();   // all waves done reading hbuf before rewrite

    // ---- gates + h update + output (owning thread, registers only) ----
    #pragma unroll
    for (int i = 0; i < 2; ++i){
      if (jv[i]){
        const int j = (jt0 + i) * 16 + lc;
        #pragma unroll
        for (int r = 0; r < 4; ++r){
          const int m = quad * 4 + r;
          const float rg = sigm(acc[i][0][r] + bR[i] + xg[i][r][0]);
          const float zg = sigm(acc[i][1][r] + bZ[i] + xg[i][r][1]);
          const float ng = tanha(xg[i][r][2] + bX[i] + rg * (acc[i][2][r] + bH[i]));
          const float hnew = (1.f - zg) * ng + zg * hprev[i][r];
          hprev[i][r] = hnew;
          hbuf[m][j] = f2bf(hnew);
          if (t < ll_r[r])
            out[(size_t)(ls_r[r] + t) * 600 + dir * HID + j] = hnew;
        }
      }
    }
  }
}

// ===========================================================================
// FALLBACK PATH (round-1, known-passing) — used when ws_size is too small.
// ===========================================================================
__global__ void prep_k(const float* __restrict__ wih_f, const float* __restrict__ whh_f,
                       const float* __restrict__ bih_f, const float* __restrict__ bhh_f,
                       const float* __restrict__ wih_b, const float* __restrict__ whh_b,
                       const float* __restrict__ bih_b, const float* __restrict__ bhh_b,
                       short* __restrict__ PkA, short* __restrict__ PkB,
                       float* __restrict__ gbias){
  const int idx = blockIdx.x * 256 + threadIdx.x;
  if (idx < 819200){
    int e = idx & 7, lane = (idx >> 3) & 63;
    int r = idx >> 9;
    int kt = r % 20; r /= 20;
    int jt = r % 20; r /= 20;
    int sec = r & 1, d = r >> 1;
    const float* wih = d ? wih_b : wih_f;
    const float* whh = d ? whh_b : whh_f;
    int j = jt * 16 + (lane & 15);
    int k = kt * 32 + (lane >> 4) * 8 + e;
    float v = 0.f;
    if (j < HID){
      int row = sec * HID + j;
      if (k < HID)                    v = wih[row * HID + k];
      else if (k >= 320 && k < 620)   v = whh[row * HID + (k - 320)];
    }
    PkA[idx] = f2bf(v);
  } else if (idx < 819200 + 409600){
    int t = idx - 819200;
    int e = t & 7, lane = (t >> 3) & 63;
    int r = t >> 9;
    int kt = r % 10; r /= 10;
    int jt = r % 20; r /= 20;
    int sec = r & 1, d = r >> 1;
    const float* w = sec ? (d ? whh_b : whh_f) : (d ? wih_b : wih_f);
    int j = jt * 16 + (lane & 15);
    int k = kt * 32 + (lane >> 4) * 8 + e;
    float v = 0.f;
    if (j < HID && k < HID) v = w[(600 + j) * HID + k];
    PkB[t] = f2bf(v);
  } else if (idx < 819200 + 409600 + 2560){
    int r3 = idx - 819200 - 409600;
    int d = r3 / 1280;
    int rem = r3 - d * 1280;
    int sec = rem / HPAD;
    int j = rem - sec * HPAD;
    const float* bih = d ? bih_b : bih_f;
    const float* bhh = d ? bhh_b : bhh_f;
    float v = 0.f;
    if (j < HID){
      if (sec == 0)      v = bih[j] + bhh[j];
      else if (sec == 1) v = bih[HID + j] + bhh[HID + j];
      else if (sec == 2) v = bih[2 * HID + j];
      else               v = bhh[2 * HID + j];
    }
    gbias[r3] = v;
  }
}

__global__ __launch_bounds__(256)
void gru_k(const float* __restrict__ node, const float* __restrict__ bias,
           const int* __restrict__ a_scope, const int* __restrict__ starts,
           const float* __restrict__ h0, const short* __restrict__ PkA,
           const short* __restrict__ PkB, const float* __restrict__ gbias,
           float* __restrict__ out){
  __shared__ __align__(16) short xbuf[16][328];
  __shared__ __align__(16) short hbuf[16][328];
  __shared__ float hfp[16][324];
  __shared__ float lbias[4][HPAD];
  __shared__ int ls[16], ll[16];

  const int dir  = blockIdx.x & 1;
  const int seg0 = (blockIdx.x >> 1) * 16;
  const int tid  = threadIdx.x;
  const int wave = tid >> 6;
  const int lane = tid & 63;
  const int quad = lane >> 4;
  const int lc   = lane & 15;
  const int l8   = lane << 3;

  if (tid < 16){ ls[tid] = starts[seg0 + tid]; ll[tid] = a_scope[seg0 + tid]; }
  for (int i = tid; i < 4 * HPAD; i += 256) ((float*)lbias)[i] = gbias[dir * (4 * HPAD) + i];
  for (int i = tid; i < 16 * HPAD; i += 256){
    int m = i / HPAD, k = i - m * HPAD;
    float v = h0[(size_t)(seg0 + m) * HPAD + k];
    hfp[m][k] = v;
    hbuf[m][k] = f2bf(v);
  }
  __syncthreads();

  const short* PA = PkA + (size_t)dir * 409600;
  const short* PB = PkB + (size_t)dir * 204800;
  const int xm = tid >> 4, xu = tid & 15;

  for (int step = 0; step < MAXLEN; ++step){
    const int t = dir ? (MAXLEN - 1 - step) : step;
    {
      const bool valid = t < ll[xm];
      const float* src = node + (size_t)(ls[xm] + t) * HID;
      for (int k = xu; k < HPAD; k += 16){
        float v = 0.f;
        if (valid && k < HID){
          v = src[k] + bias[k];
          v = v > 0.f ? v : 0.f;
        }
        xbuf[xm][k] = f2bf(v);
      }
    }
    __syncthreads();

    f4v aR[5], aZ[5], aX[5], aH[5];
    #pragma unroll
    for (int i = 0; i < 5; ++i){
      aR[i] = f4v{0.f,0.f,0.f,0.f}; aZ[i] = f4v{0.f,0.f,0.f,0.f};
      aX[i] = f4v{0.f,0.f,0.f,0.f}; aH[i] = f4v{0.f,0.f,0.f,0.f};
    }
    #pragma unroll 2
    for (int kt = 0; kt < 10; ++kt){
      const int k0 = kt * 32 + quad * 8;
      const s8v a = *(const s8v*)&xbuf[lc][k0];
      #pragma unroll
      for (int i = 0; i < 5; ++i){
        const int jt = wave * 5 + i;
        const s8v bR = *(const s8v*)(PA + (size_t)((jt)      * 20 + kt) * 512 + l8);
        aR[i] = __builtin_amdgcn_mfma_f32_16x16x32_bf16(a, bR, aR[i], 0, 0, 0);
        const s8v bZ = *(const s8v*)(PA + (size_t)((20 + jt) * 20 + kt) * 512 + l8);
        aZ[i] = __builtin_amdgcn_mfma_f32_16x16x32_bf16(a, bZ, aZ[i], 0, 0, 0);
        const s8v bX = *(const s8v*)(PB + (size_t)((jt)      * 10 + kt) * 512 + l8);
        aX[i] = __builtin_amdgcn_mfma_f32_16x16x32_bf16(a, bX, aX[i], 0, 0, 0);
      }
    }
    #pragma unroll 2
    for (int kt = 0; kt < 10; ++kt){
      const int k0 = kt * 32 + quad * 8;
      const s8v a = *(const s8v*)&hbuf[lc][k0];
      #pragma unroll
      for (int i = 0; i < 5; ++i){
        const int jt = wave * 5 + i;
        const s8v bR = *(const s8v*)(PA + (size_t)((jt)      * 20 + 10 + kt) * 512 + l8);
        aR[i] = __builtin_amdgcn_mfma_f32_16x16x32_bf16(a, bR, aR[i], 0, 0, 0);
        const s8v bZ = *(const s8v*)(PA + (size_t)((20 + jt) * 20 + 10 + kt) * 512 + l8);
        aZ[i] = __builtin_amdgcn_mfma_f32_16x16x32_bf16(a, bZ, aZ[i], 0, 0, 0);
        const s8v bH = *(const s8v*)(PB + (size_t)((20 + jt) * 10 + kt) * 512 + l8);
        aH[i] = __builtin_amdgcn_mfma_f32_16x16x32_bf16(a, bH, aH[i], 0, 0, 0);
      }
    }
    __syncthreads();

    #pragma unroll
    for (int i = 0; i < 5; ++i){
      const int j = wave * 80 + i * 16 + lc;
      if (j < HID){
        const float bR = lbias[0][j], bZ = lbias[1][j];
        const float bX = lbias[2][j], bH = lbias[3][j];
        #pragma unroll
        for (int r = 0; r < 4; ++r){
          const int m = quad * 4 + r;
          const float rg = sigm(aR[i][r] + bR);
          const float zg = sigm(aZ[i][r] + bZ);
          const float ng = tanha(aX[i][r] + bX + rg * (aH[i][r] + bH));
          const float hold = hfp[m][j];
          const float hnew = (1.f - zg) * ng + zg * hold;
          hfp[m][j] = hnew;
          hbuf[m][j] = f2bf(hnew);
          if (t < ll[m])
            out[(size_t)(ls[m] + t) * 600 + dir * HID + j] = hnew;
        }
      }
    }
  }
}

// ---------------------------------------------------------------------------
extern "C" void kernel_launch(void* const* d_in, const int* in_sizes, int n_in,
                              void* d_out, int out_size, void* d_ws, size_t ws_size,
                              hipStream_t stream){
  const float* node    = (const float*)d_in[0];
  const int*   a_scope = (const int*)  d_in[1];
  // d_in[2] = max_len (always 128, hardcoded)
  const float* bias    = (const float*)d_in[3];
  const float* wih_f   = (const float*)d_in[4];
  const float* whh_f   = (const float*)d_in[5];
  const float* bih_f   = (const float*)d_in[6];
  const float* bhh_f   = (const float*)d_in[7];
  const float* wih_b   = (const float*)d_in[8];
  const float* whh_b   = (const float*)d_in[9];
  const float* bih_b   = (const float*)d_in[10];
  const float* bhh_b   = (const float*)d_in[11];
  float* out = (float*)d_out;

  char* ws = (char*)d_ws;
  int*   starts = (int*)  (ws + 0);          //     8,192 B
  float* h0     = (float*)(ws + 8192);       // 2,621,440 B -> 2,629,632

  scan_starts_k<<<1, 1024, 0, stream>>>(a_scope, starts);
  h0_max_k<<<NSEG, HPAD, 0, stream>>>(node, a_scope, starts, h0);

  const size_t FAST_NEED = 476956672ull;     // ~477 MB (xp bf16 both dirs)
  if (ws_size >= FAST_NEED){
    short* PkH = (short*)(ws + 2629632);     // 1,228,800 B
    short* PkI = (short*)(ws + 3858432);     // 1,228,800 B
    float* gb  = (float*)(ws + 5087232);     //    10,240 B
    short* xpb = (short*)(ws + 5097472);     // 471,859,200 B
    prep2_k<<<4810, 256, 0, stream>>>(wih_f, whh_f, bih_f, bhh_f,
                                      wih_b, whh_b, bih_b, bhh_b, PkH, PkI, gb);
    xp_gemm_k<<<2048, 256, 0, stream>>>(node, bias, PkI, xpb);
    gru3_k<<<256, 640, 0, stream>>>(a_scope, starts, h0, PkH, gb, xpb, out);
  } else {
    short* PkA   = (short*)(ws + 2629632);   // 1,638,400 B
    short* PkB   = (short*)(ws + 4268032);   //   819,200 B
    float* gbias = (float*)(ws + 5087232);   //    10,240 B
    prep_k<<<4810, 256, 0, stream>>>(wih_f, whh_f, bih_f, bhh_f,
                                     wih_b, whh_b, bih_b, bhh_b, PkA, PkB, gbias);
    gru_k<<<256, 256, 0, stream>>>(node, bias, a_scope, starts, h0, PkA, PkB, gbias, out);
  }
}